// Round 1
// baseline (55.395 us; speedup 1.0000x reference)
//
#include <hip/hip_runtime.h>

#define F_ALPHA 0.25f
#define F_EPS   1e-8f

// Kernel A: per-(pred, class) focal cost table.
// ftab[n*C + c] = pos_cost - neg_cost for p = sigmoid(logit[n,c])
__global__ void focal_table_kernel(const float* __restrict__ logits,
                                   float* __restrict__ ftab, int total) {
    int i = blockIdx.x * blockDim.x + threadIdx.x;
    if (i >= total) return;
    float x = logits[i];
    float p = 1.0f / (1.0f + expf(-x));
    float om = 1.0f - p;
    float pos = F_ALPHA * om * om * (-logf(p + F_EPS));
    float neg = (1.0f - F_ALPHA) * p * p * (-logf(om + F_EPS));
    ftab[i] = pos - neg;
}

// Kernel B: one thread -> 4 consecutive targets for one pred (float4 store).
__global__ void cost_kernel(const float* __restrict__ pred_boxes,
                            const float4* __restrict__ tgt_boxes,
                            const int* __restrict__ tgt_ids,
                            const float* __restrict__ ftab,
                            float4* __restrict__ out,
                            int N, int T4, int C) {
    int idx = blockIdx.x * blockDim.x + threadIdx.x;
    if (idx >= N * T4) return;
    int n  = idx / T4;
    int t4 = idx - n * T4;

    float4 pb = ((const float4*)pred_boxes)[n];   // cx, cy, w, h
    float px1 = pb.x - 0.5f * pb.z, py1 = pb.y - 0.5f * pb.w;
    float px2 = pb.x + 0.5f * pb.z, py2 = pb.y + 0.5f * pb.w;
    float parea = pb.z * pb.w;
    const float* __restrict__ frow = ftab + (long)n * C;

    float res[4];
    int t0 = t4 * 4;
#pragma unroll
    for (int j = 0; j < 4; ++j) {
        int t = t0 + j;
        float4 tb = tgt_boxes[t];                 // cx, cy, w, h
        float tx1 = tb.x - 0.5f * tb.z, ty1 = tb.y - 0.5f * tb.w;
        float tx2 = tb.x + 0.5f * tb.z, ty2 = tb.y + 0.5f * tb.w;
        float tarea = tb.z * tb.w;

        // L1 cost in cxcywh space
        float l1 = fabsf(pb.x - tb.x) + fabsf(pb.y - tb.y)
                 + fabsf(pb.z - tb.z) + fabsf(pb.w - tb.w);

        // IoU
        float ix1 = fmaxf(px1, tx1), iy1 = fmaxf(py1, ty1);
        float ix2 = fminf(px2, tx2), iy2 = fminf(py2, ty2);
        float iw = fmaxf(ix2 - ix1, 0.0f), ih = fmaxf(iy2 - iy1, 0.0f);
        float inter = iw * ih;
        float uni = parea + tarea - inter;
        float iou = inter / uni;

        // enclosing box
        float ex1 = fminf(px1, tx1), ey1 = fminf(py1, ty1);
        float ex2 = fmaxf(px2, tx2), ey2 = fmaxf(py2, ty2);
        float ew = fmaxf(ex2 - ex1, 0.0f), eh = fmaxf(ey2 - ey1, 0.0f);
        float earea = ew * eh;
        float giou = iou - (earea - uni) / earea;

        float cls = frow[tgt_ids[t]];
        res[j] = 5.0f * l1 + 2.0f * cls - 2.0f * giou;  // cost_giou = -giou
    }
    out[idx] = make_float4(res[0], res[1], res[2], res[3]);
}

extern "C" void kernel_launch(void* const* d_in, const int* in_sizes, int n_in,
                              void* d_out, int out_size, void* d_ws, size_t ws_size,
                              hipStream_t stream) {
    const float* logits = (const float*)d_in[0];   // [bs, Q, C]
    const float* pboxes = (const float*)d_in[1];   // [bs, Q, 4]
    const float* tboxes = (const float*)d_in[2];   // [T, 4]
    const int*   tids   = (const int*)d_in[3];     // [T]

    int N = in_sizes[1] / 4;          // bs*Q = 14400
    int C = in_sizes[0] / N;          // 91
    int T = in_sizes[2] / 4;          // 1600

    float* ftab = (float*)d_ws;       // N*C floats = 5.24 MB

    int totalA = N * C;
    focal_table_kernel<<<(totalA + 255) / 256, 256, 0, stream>>>(logits, ftab, totalA);

    int T4 = T / 4;                   // T = 1600 -> 400
    long totalB = (long)N * T4;       // 5.76M threads
    cost_kernel<<<(int)((totalB + 255) / 256), 256, 0, stream>>>(
        pboxes, (const float4*)tboxes, tids, ftab, (float4*)d_out, N, T4, C);
}

// Round 2
// 46.478 us; speedup vs baseline: 1.1918x; 1.1918x over previous
//
#include <hip/hip_runtime.h>

#define F_ALPHA 0.25f
#define F_EPS   1e-8f

// Kernel A: per-(pred, class) focal cost table.
// ftab[n*C + c] = pos_cost - neg_cost for p = sigmoid(logit[n,c])
__global__ void focal_table_kernel(const float* __restrict__ logits,
                                   float* __restrict__ ftab, int total) {
    int i = blockIdx.x * blockDim.x + threadIdx.x;
    if (i >= total) return;
    float x = logits[i];
    float p = 1.0f / (1.0f + expf(-x));
    float om = 1.0f - p;
    float pos = F_ALPHA * om * om * (-logf(p + F_EPS));
    float neg = (1.0f - F_ALPHA) * p * p * (-logf(om + F_EPS));
    ftab[i] = pos - neg;
}

// Kernel B: one thread -> 4 targets strided by T/4 (all lane accesses unit-stride).
__global__ void cost_kernel(const float4* __restrict__ pred_boxes,
                            const float4* __restrict__ tgt_boxes,
                            const int* __restrict__ tgt_ids,
                            const float* __restrict__ ftab,
                            float* __restrict__ out,
                            int N, int T, int C) {
    const int T4 = T >> 2;                       // 400
    int idx = blockIdx.x * blockDim.x + threadIdx.x;
    if (idx >= N * T4) return;
    int n = idx / T4;
    int t = idx - n * T4;

    float4 pb = pred_boxes[n];                   // cx, cy, w, h (wave-mostly-uniform)
    float px1 = pb.x - 0.5f * pb.z, py1 = pb.y - 0.5f * pb.w;
    float px2 = pb.x + 0.5f * pb.z, py2 = pb.y + 0.5f * pb.w;
    float parea = pb.z * pb.w;
    const float* __restrict__ frow = ftab + (size_t)n * C;
    float* __restrict__ orow = out + (size_t)n * T;

#pragma unroll
    for (int j = 0; j < 4; ++j) {
        int tt = t + j * T4;                     // lanes -> consecutive tt
        float4 tb = tgt_boxes[tt];               // unit-stride float4 load
        float tx1 = tb.x - 0.5f * tb.z, ty1 = tb.y - 0.5f * tb.w;
        float tx2 = tb.x + 0.5f * tb.z, ty2 = tb.y + 0.5f * tb.w;
        float tarea = tb.z * tb.w;

        // L1 cost in cxcywh space
        float l1 = fabsf(pb.x - tb.x) + fabsf(pb.y - tb.y)
                 + fabsf(pb.z - tb.z) + fabsf(pb.w - tb.w);

        // intersection
        float ix1 = fmaxf(px1, tx1), iy1 = fmaxf(py1, ty1);
        float ix2 = fminf(px2, tx2), iy2 = fminf(py2, ty2);
        float iw = fmaxf(ix2 - ix1, 0.0f), ih = fmaxf(iy2 - iy1, 0.0f);
        float inter = iw * ih;
        float uni = parea + tarea - inter;

        // enclosing box
        float ex1 = fminf(px1, tx1), ey1 = fminf(py1, ty1);
        float ex2 = fmaxf(px2, tx2), ey2 = fmaxf(py2, ty2);
        float ew = fmaxf(ex2 - ex1, 0.0f), eh = fmaxf(ey2 - ey1, 0.0f);
        float earea = ew * eh;

        // fast reciprocals (v_rcp_f32, ~1 ulp; threshold headroom is ~7x)
        float r_u = __builtin_amdgcn_rcpf(uni);
        float r_e = __builtin_amdgcn_rcpf(earea);

        float cls = frow[tgt_ids[tt]];
        // 5*l1 + 2*cls + 2*(-giou); -giou = 1 - inter/uni - uni/earea
        float v = 2.0f + 5.0f * l1 + 2.0f * cls
                - 2.0f * (inter * r_u) - 2.0f * (uni * r_e);
        orow[tt] = v;                            // unit-stride dword store
    }
}

extern "C" void kernel_launch(void* const* d_in, const int* in_sizes, int n_in,
                              void* d_out, int out_size, void* d_ws, size_t ws_size,
                              hipStream_t stream) {
    const float* logits = (const float*)d_in[0];   // [bs, Q, C]
    const float* pboxes = (const float*)d_in[1];   // [bs, Q, 4]
    const float* tboxes = (const float*)d_in[2];   // [T, 4]
    const int*   tids   = (const int*)d_in[3];     // [T]

    int N = in_sizes[1] / 4;          // bs*Q = 14400
    int C = in_sizes[0] / N;          // 91
    int T = in_sizes[2] / 4;          // 1600

    float* ftab = (float*)d_ws;       // N*C floats = 5.24 MB

    int totalA = N * C;
    focal_table_kernel<<<(totalA + 255) / 256, 256, 0, stream>>>(logits, ftab, totalA);

    int T4 = T / 4;
    long totalB = (long)N * T4;       // 5.76M threads
    cost_kernel<<<(int)((totalB + 255) / 256), 256, 0, stream>>>(
        (const float4*)pboxes, (const float4*)tboxes, tids, ftab, (float*)d_out,
        N, T, C);
}

// Round 3
// 39.572 us; speedup vs baseline: 1.3998x; 1.1745x over previous
//
#include <hip/hip_runtime.h>

#define F_ALPHA 0.25f
#define F_EPS   1e-8f

// One block per prediction n (grid = bs*Q = 14400, 256 threads).
// Phase 1: lanes < C compute the focal class-cost row for this n into LDS.
// Phase 2: threads sweep targets t = tid, tid+256, ... (unit-stride loads/stores).
// All pred-side quantities are scalar (address depends only on blockIdx).
__global__ void __launch_bounds__(256)
fused_cost_kernel(const float* __restrict__ logits,      // [N, C]
                  const float4* __restrict__ pred_boxes, // [N]
                  const float4* __restrict__ tgt_boxes,  // [T]
                  const int* __restrict__ tgt_ids,       // [T]
                  float* __restrict__ out,               // [N, T]
                  int C, int T) {
    __shared__ float fcls[128];                          // C <= 128
    const int n   = blockIdx.x;
    const int tid = threadIdx.x;

    // ---- phase 1: focal table for this pred's logits row ----
    const float* lrow = logits + (size_t)n * C;          // scalar base
    for (int c = tid; c < C; c += 256) {
        float x = lrow[c];
        float p = 1.0f / (1.0f + expf(-x));
        float om = 1.0f - p;
        float pos = F_ALPHA * om * om * (-logf(p + F_EPS));
        float neg = (1.0f - F_ALPHA) * p * p * (-logf(om + F_EPS));
        fcls[c] = pos - neg;
    }

    // pred box -> scalar registers (uniform across block)
    float4 pb = pred_boxes[n];                           // s_load_dwordx4
    float px1 = pb.x - 0.5f * pb.z, py1 = pb.y - 0.5f * pb.w;
    float px2 = pb.x + 0.5f * pb.z, py2 = pb.y + 0.5f * pb.w;
    float parea = pb.z * pb.w;

    __syncthreads();

    float* __restrict__ orow = out + (size_t)n * T;

    // ---- phase 2: sweep targets ----
    for (int t = tid; t < T; t += 256) {
        float4 tb = tgt_boxes[t];                        // unit-stride float4
        int id = tgt_ids[t];                             // unit-stride dword
        float cls = fcls[id];                            // LDS gather (4B)

        float tx1 = tb.x - 0.5f * tb.z, ty1 = tb.y - 0.5f * tb.w;
        float tx2 = tb.x + 0.5f * tb.z, ty2 = tb.y + 0.5f * tb.w;
        float tarea = tb.z * tb.w;

        // L1 cost (cxcywh space)
        float l1 = fabsf(pb.x - tb.x) + fabsf(pb.y - tb.y)
                 + fabsf(pb.z - tb.z) + fabsf(pb.w - tb.w);

        // intersection / union
        float ix1 = fmaxf(px1, tx1), iy1 = fmaxf(py1, ty1);
        float ix2 = fminf(px2, tx2), iy2 = fminf(py2, ty2);
        float iw = fmaxf(ix2 - ix1, 0.0f), ih = fmaxf(iy2 - iy1, 0.0f);
        float inter = iw * ih;
        float uni = parea + tarea - inter;

        // enclosing box (inputs uniform [0,1): w,h >= 0 -> no clamp needed)
        float ex1 = fminf(px1, tx1), ey1 = fminf(py1, ty1);
        float ex2 = fmaxf(px2, tx2), ey2 = fmaxf(py2, ty2);
        float earea = (ex2 - ex1) * (ey2 - ey1);

        float r_u = __builtin_amdgcn_rcpf(uni);
        float r_e = __builtin_amdgcn_rcpf(earea);

        // 5*l1 + 2*cls + 2*(-giou);  -giou = 1 - inter/uni - uni/earea
        float v = 2.0f + 5.0f * l1 + 2.0f * cls
                - 2.0f * (inter * r_u) - 2.0f * (uni * r_e);
        orow[t] = v;                                     // unit-stride dword store
    }
}

extern "C" void kernel_launch(void* const* d_in, const int* in_sizes, int n_in,
                              void* d_out, int out_size, void* d_ws, size_t ws_size,
                              hipStream_t stream) {
    const float* logits = (const float*)d_in[0];   // [bs, Q, C]
    const float* pboxes = (const float*)d_in[1];   // [bs, Q, 4]
    const float* tboxes = (const float*)d_in[2];   // [T, 4]
    const int*   tids   = (const int*)d_in[3];     // [T]

    int N = in_sizes[1] / 4;          // bs*Q = 14400
    int C = in_sizes[0] / N;          // 91
    int T = in_sizes[2] / 4;          // 1600

    fused_cost_kernel<<<N, 256, 0, stream>>>(
        logits, (const float4*)pboxes, (const float4*)tboxes, tids,
        (float*)d_out, C, T);
}

// Round 4
// 36.741 us; speedup vs baseline: 1.5077x; 1.0770x over previous
//
#include <hip/hip_runtime.h>

#define F_ALPHA 0.25f
#define F_EPS   1e-8f
#define NB 4   // preds per block: amortizes target loads/conversions 4x

// Grid = ceil(N/NB) blocks x 256 threads. Each block handles NB preds.
// Phase 1: NB focal tables (pre-scaled: 2*cls+2) into LDS.
// Phase 2: sweep targets; per target, load/convert once, then NB cost rows.
__global__ void __launch_bounds__(256)
fused_cost_kernel(const float* __restrict__ logits,      // [N, C]
                  const float4* __restrict__ pred_boxes, // [N]
                  const float4* __restrict__ tgt_boxes,  // [T]
                  const int* __restrict__ tgt_ids,       // [T]
                  float* __restrict__ out,               // [N, T]
                  int N, int C, int T) {
    __shared__ float fcls[NB][96];                       // C <= 96, padded rows
    const int n0  = blockIdx.x * NB;
    const int tid = threadIdx.x;

    // ---- phase 1: focal tables for the NB logits rows ----
    if (tid < C) {
#pragma unroll
        for (int i = 0; i < NB; ++i) {
            if (n0 + i < N) {
                float x = logits[(size_t)(n0 + i) * C + tid];
                float p = 1.0f / (1.0f + expf(-x));
                float om = 1.0f - p;
                float pos = F_ALPHA * om * om * (-logf(p + F_EPS));
                float neg = (1.0f - F_ALPHA) * p * p * (-logf(om + F_EPS));
                fcls[i][tid] = 2.0f * (pos - neg) + 2.0f; // fold 2*cls and +2
            }
        }
    }

    // pred-side params, block-uniform, fully unrolled -> registers
    float pcx[NB], pcy[NB], pw[NB], ph[NB];
    float px1[NB], py1[NB], px2[NB], py2[NB], parea[NB];
#pragma unroll
    for (int i = 0; i < NB; ++i) {
        int n = min(n0 + i, N - 1);
        float4 pb = pred_boxes[n];
        pcx[i] = pb.x; pcy[i] = pb.y; pw[i] = pb.z; ph[i] = pb.w;
        px1[i] = pb.x - 0.5f * pb.z;  py1[i] = pb.y - 0.5f * pb.w;
        px2[i] = pb.x + 0.5f * pb.z;  py2[i] = pb.y + 0.5f * pb.w;
        parea[i] = pb.z * pb.w;
    }

    __syncthreads();

    // ---- phase 2: sweep targets ----
    for (int t = tid; t < T; t += 256) {
        float4 tb = tgt_boxes[t];                        // unit-stride float4
        int id = tgt_ids[t];                             // unit-stride dword
        float tx1 = tb.x - 0.5f * tb.z, ty1 = tb.y - 0.5f * tb.w;
        float tx2 = tb.x + 0.5f * tb.z, ty2 = tb.y + 0.5f * tb.w;
        float tarea = tb.z * tb.w;

#pragma unroll
        for (int i = 0; i < NB; ++i) {
            if (n0 + i < N) {                            // uniform scalar branch
                float cls2 = fcls[i][id];                // LDS gather (4B)

                float l1 = (fabsf(pcx[i] - tb.x) + fabsf(pcy[i] - tb.y))
                         + (fabsf(pw[i] - tb.z) + fabsf(ph[i] - tb.w));

                float ix1 = fmaxf(px1[i], tx1), iy1 = fmaxf(py1[i], ty1);
                float ix2 = fminf(px2[i], tx2), iy2 = fminf(py2[i], ty2);
                float iw = fmaxf(ix2 - ix1, 0.0f), ih = fmaxf(iy2 - iy1, 0.0f);
                float inter = iw * ih;
                float uni = parea[i] + tarea - inter;

                float ex1 = fminf(px1[i], tx1), ey1 = fminf(py1[i], ty1);
                float ex2 = fmaxf(px2[i], tx2), ey2 = fmaxf(py2[i], ty2);
                float earea = (ex2 - ex1) * (ey2 - ey1);  // wh >= 0 for [0,1) boxes

                float r_u = __builtin_amdgcn_rcpf(uni);
                float r_e = __builtin_amdgcn_rcpf(earea);

                float v = fmaf(5.0f, l1, cls2);           // 5*l1 + 2*cls + 2
                v = fmaf(-2.0f, inter * r_u, v);
                v = fmaf(-2.0f, uni * r_e, v);

                // dead-on-arrival data: don't pollute L2 (target reads live there)
                __builtin_nontemporal_store(v, out + (size_t)(n0 + i) * T + t);
            }
        }
    }
}

extern "C" void kernel_launch(void* const* d_in, const int* in_sizes, int n_in,
                              void* d_out, int out_size, void* d_ws, size_t ws_size,
                              hipStream_t stream) {
    const float* logits = (const float*)d_in[0];   // [bs, Q, C]
    const float* pboxes = (const float*)d_in[1];   // [bs, Q, 4]
    const float* tboxes = (const float*)d_in[2];   // [T, 4]
    const int*   tids   = (const int*)d_in[3];     // [T]

    int N = in_sizes[1] / 4;          // bs*Q = 14400
    int C = in_sizes[0] / N;          // 91
    int T = in_sizes[2] / 4;          // 1600

    int grid = (N + NB - 1) / NB;     // 3600
    fused_cost_kernel<<<grid, 256, 0, stream>>>(
        logits, (const float4*)pboxes, (const float4*)tboxes, tids,
        (float*)d_out, N, C, T);
}

// Round 5
// 32.937 us; speedup vs baseline: 1.6818x; 1.1155x over previous
//
#include <hip/hip_runtime.h>

#define F_ALPHA 0.25f
#define F_EPS   1e-8f
#define NB 4   // preds per block

// Grid = N/NB blocks x 256 threads.
// Phase 1: wave w computes the focal row (pre-scaled 2*cls+2) for pred n0+w.
// Phase 2: sweep targets unrolled x2; per target: one float4 load + one id load,
//          then NB branchless cost evaluations with precomputed row pointers.
__global__ void __launch_bounds__(256)
fused_cost_kernel(const float* __restrict__ logits,      // [N, C]
                  const float4* __restrict__ pred_boxes, // [N]
                  const float4* __restrict__ tgt_boxes,  // [T]
                  const int* __restrict__ tgt_ids,       // [T]
                  float* __restrict__ out,               // [N, T]
                  int N, int C, int T) {
    __shared__ float fcls[NB][96];                       // C <= 96
    const int n0  = blockIdx.x * NB;
    const int tid = threadIdx.x;

    // ---- phase 1: one wave per pred row (NB == 4 waves) ----
    {
        const int w = tid >> 6, l = tid & 63;
        const int n = min(n0 + w, N - 1);
        const float* lrow = logits + (size_t)n * C;
        for (int c = l; c < C; c += 64) {
            float x = lrow[c];
            float p = 1.0f / (1.0f + expf(-x));
            float om = 1.0f - p;
            float pos = F_ALPHA * om * om * (-logf(p + F_EPS));
            float neg = (1.0f - F_ALPHA) * p * p * (-logf(om + F_EPS));
            fcls[w][c] = 2.0f * (pos - neg) + 2.0f;      // fold 2*cls and +2
        }
    }

    // pred-side params (block-uniform) + output row pointers
    float pcx[NB], pcy[NB], pw_[NB], ph_[NB];
    float px1[NB], py1[NB], px2[NB], py2[NB], parea[NB];
    float* op[NB];
#pragma unroll
    for (int i = 0; i < NB; ++i) {
        const int n = min(n0 + i, N - 1);                // no-op when N % NB == 0
        float4 pb = pred_boxes[n];
        pcx[i] = pb.x; pcy[i] = pb.y; pw_[i] = pb.z; ph_[i] = pb.w;
        px1[i] = pb.x - 0.5f * pb.z;  py1[i] = pb.y - 0.5f * pb.w;
        px2[i] = pb.x + 0.5f * pb.z;  py2[i] = pb.y + 0.5f * pb.w;
        parea[i] = pb.z * pb.w;
        op[i] = out + (size_t)n * T;
    }
    __syncthreads();

    auto body = [&](int t) {
        float4 tb = tgt_boxes[t];                        // unit-stride float4
        int id = tgt_ids[t];                             // unit-stride dword
        float tx1 = tb.x - 0.5f * tb.z, ty1 = tb.y - 0.5f * tb.w;
        float tx2 = tb.x + 0.5f * tb.z, ty2 = tb.y + 0.5f * tb.w;
        float tarea = tb.z * tb.w;
#pragma unroll
        for (int i = 0; i < NB; ++i) {
            float cls2 = fcls[i][id];                    // LDS gather (4B)

            float l1 = (fabsf(pcx[i] - tb.x) + fabsf(pcy[i] - tb.y))
                     + (fabsf(pw_[i] - tb.z) + fabsf(ph_[i] - tb.w));

            float ix1 = fmaxf(px1[i], tx1), iy1 = fmaxf(py1[i], ty1);
            float ix2 = fminf(px2[i], tx2), iy2 = fminf(py2[i], ty2);
            float iw = fmaxf(ix2 - ix1, 0.0f), ih = fmaxf(iy2 - iy1, 0.0f);
            float inter = iw * ih;
            float uni = parea[i] + tarea - inter;

            float ex1 = fminf(px1[i], tx1), ey1 = fminf(py1[i], ty1);
            float ex2 = fmaxf(px2[i], tx2), ey2 = fmaxf(py2[i], ty2);
            float earea = (ex2 - ex1) * (ey2 - ey1);     // wh >= 0 for [0,1) boxes

            float v = fmaf(5.0f, l1, cls2);              // 5*l1 + 2*cls + 2
            v = fmaf(-2.0f, inter * __builtin_amdgcn_rcpf(uni), v);
            v = fmaf(-2.0f, uni * __builtin_amdgcn_rcpf(earea), v);
            op[i][t] = v;                                // plain coalesced store
        }
    };

    // ---- phase 2: unrolled-by-2 target sweep ----
    int t = tid;
    for (; t + 256 < T; t += 512) { body(t); body(t + 256); }
    for (; t < T; t += 256) body(t);
}

extern "C" void kernel_launch(void* const* d_in, const int* in_sizes, int n_in,
                              void* d_out, int out_size, void* d_ws, size_t ws_size,
                              hipStream_t stream) {
    const float* logits = (const float*)d_in[0];   // [bs, Q, C]
    const float* pboxes = (const float*)d_in[1];   // [bs, Q, 4]
    const float* tboxes = (const float*)d_in[2];   // [T, 4]
    const int*   tids   = (const int*)d_in[3];     // [T]

    int N = in_sizes[1] / 4;          // bs*Q = 14400
    int C = in_sizes[0] / N;          // 91
    int T = in_sizes[2] / 4;          // 1600

    int grid = (N + NB - 1) / NB;     // 3600
    fused_cost_kernel<<<grid, 256, 0, stream>>>(
        logits, (const float4*)pboxes, (const float4*)tboxes, tids,
        (float*)d_out, N, C, T);
}